// Round 8
// baseline (122.204 us; speedup 1.0000x reference)
//
#include <hip/hip_runtime.h>
#include <math.h>

#define N_PTS    65536
#define N_CTR    1024      // per set
#define NCELLS   128       // 8x16 fat cells (0.125 x 0.0625), ~512 pts each
#define CELL_CAP 768
#define CHUNK    512       // centers per block -> 2 chunks per set
#define CUT      44.0f     // cull threshold (log2 units): e < 2^-44 dropped
#define LOG2E    1.4426950408889634f

#if __has_builtin(__builtin_amdgcn_exp2f)
#define EXP2(v) __builtin_amdgcn_exp2f(v)
#else
#define EXP2(v) exp2f(v)
#endif

// ws: RA/RB (float4[3072]): poly+acc coeffs; RC (float[3072]): k3;
//     RT (float4[3072]): (cx, cy, d1*L, d2*L) cull data;
//     cnt[128], idxl[128*768] u16 point buckets.
// s = za + x*(zb+zc*x) + y*(zd+ze*y); e = exp2(s)
// set0: ux = x*S(k0 e)+S(k1 e), uy = y*S(k2 e)+S(k3 e)
// set1: P = S(k0 e), Px = x*S(k1 e)+S(k2 e);  set2: Q,Qy analog.

__global__ __launch_bounds__(256) void prep_kernel(
    const float* __restrict__ h0, const float* __restrict__ c0, const float* __restrict__ w0,
    const float* __restrict__ h1, const float* __restrict__ c1, const float* __restrict__ w1,
    const float* __restrict__ h2, const float* __restrict__ c2, const float* __restrict__ w2,
    float4* __restrict__ RA, float4* __restrict__ RB, float* __restrict__ RC,
    float4* __restrict__ RT, unsigned int* __restrict__ cnt,
    float4* __restrict__ out_zero)
{
    const int idx = blockIdx.x * 256 + threadIdx.x;   // 0..3071

    { // zero outputs: 3072 x 32 float4 = 393216 floats
        float4 z = make_float4(0.f, 0.f, 0.f, 0.f);
        float4* o = out_zero + idx * 32;
        #pragma unroll
        for (int t = 0; t < 32; ++t) o[t] = z;
    }
    if (idx < NCELLS) cnt[idx] = 0u;
    if (idx >= 3 * N_CTR) return;

    const int set = idx >> 10;
    const int j   = idx & (N_CTR - 1);
    const float*  h = (set == 0) ? h0 : ((set == 1) ? h1 : h2);
    const float2* c = (const float2*)((set == 0) ? c0 : ((set == 1) ? c1 : c2));
    const float2* w = (const float2*)((set == 0) ? w0 : ((set == 1) ? w1 : w2));

    float2 cj = c[j];
    float2 wj = w[j];
    float  hh = h[j];
    float d1 = wj.x * wj.x;
    float d2 = wj.y * wj.y;
    float zb =  2.f * cj.x * d1 * LOG2E;
    float zc = -d1 * LOG2E;
    float zd =  2.f * cj.y * d2 * LOG2E;
    float ze = -d2 * LOG2E;
    float za = -(cj.x * cj.x * d1 + cj.y * cj.y * d2) * LOG2E;
    float k0, k1, k2, k3;
    if (set == 0) {
        k0 = -2.f * hh * d1;  k1 = 2.f * hh * d1 * cj.x;
        k2 = -2.f * hh * d2;  k3 = 2.f * hh * d2 * cj.y;
    } else if (set == 1) {
        k0 = hh;  k1 = -2.f * hh * d1;  k2 = 2.f * hh * d1 * cj.x;  k3 = 0.f;
    } else {
        k0 = hh;  k1 = -2.f * hh * d2;  k2 = 2.f * hh * d2 * cj.y;  k3 = 0.f;
    }
    RA[idx] = make_float4(zb, zc, zd, ze);
    RB[idx] = make_float4(za, k0, k1, k2);
    RC[idx] = k3;
    RT[idx] = make_float4(cj.x, cj.y, d1 * LOG2E, d2 * LOG2E);
}

__global__ __launch_bounds__(256) void bucket_kernel(
    const float* __restrict__ x,
    unsigned int* __restrict__ cnt,
    unsigned short* __restrict__ idxl)
{
    const int i = blockIdx.x * 256 + threadIdx.x;   // 65536
    float2 p = ((const float2*)x)[i];
    int cx = (int)(p.x * 8.f);  cx = cx > 7  ? 7  : (cx < 0 ? 0 : cx);
    int cy = (int)(p.y * 16.f); cy = cy > 15 ? 15 : (cy < 0 ? 0 : cy);
    const int cell = cy * 8 + cx;
    unsigned int slot = atomicAdd(&cnt[cell], 1u);
    if (slot < CELL_CAP) idxl[cell * CELL_CAP + slot] = (unsigned short)i;
}

__global__ __launch_bounds__(256) void srbf_main(
    const float* __restrict__ x,
    const float4* __restrict__ RA, const float4* __restrict__ RB,
    const float*  __restrict__ RC, const float4* __restrict__ RT,
    const unsigned int* __restrict__ cnt,
    const unsigned short* __restrict__ idxl,
    float* __restrict__ out)
{
    __shared__ float4 sA[CHUNK];
    __shared__ float4 sB[CHUNK];
    __shared__ float  sC[CHUNK];
    __shared__ int    wtot[4];

    const int bid   = blockIdx.x;       // 0..767 (3/CU exact)
    const int set   = bid >> 8;
    const int r     = bid & 255;
    const int fat   = r >> 1;
    const int chunk = r & 1;
    const int tid   = threadIdx.x;
    const int lane  = tid & 63;
    const int wv    = tid >> 6;
    const int cbase = set * N_CTR + chunk * CHUNK;

    const float cx0 = (float)(fat & 7) * 0.125f;
    const float cy0 = (float)(fat >> 3) * 0.0625f;
    const float cx1 = cx0 + 0.125f;
    const float cy1 = cy0 + 0.0625f;

    // ---- phase 1: cull this chunk's 512 centers (deterministic wave-scan) ----
    const int j0 = cbase + wv * 128 + lane;
    const int j1 = j0 + 64;
    float4 T0 = RT[j0];
    float4 T1 = RT[j1];
    float ax0 = fmaxf(fmaxf(cx0 - T0.x, T0.x - cx1), 0.f);
    float ay0 = fmaxf(fmaxf(cy0 - T0.y, T0.y - cy1), 0.f);
    float q0  = ax0 * ax0 * T0.z + ay0 * ay0 * T0.w;
    float ax1 = fmaxf(fmaxf(cx0 - T1.x, T1.x - cx1), 0.f);
    float ay1 = fmaxf(fmaxf(cy0 - T1.y, T1.y - cy1), 0.f);
    float q1  = ax1 * ax1 * T1.z + ay1 * ay1 * T1.w;
    const bool live0 = q0 < CUT;
    const bool live1 = q1 < CUT;
    unsigned long long ms0 = __ballot(live0);
    unsigned long long ms1 = __ballot(live1);
    const int c0 = __popcll(ms0);
    if (lane == 0) wtot[wv] = c0 + __popcll(ms1);
    __syncthreads();
    int base = 0, m = 0;
    #pragma unroll
    for (int w2 = 0; w2 < 4; ++w2) {
        int t = wtot[w2];
        m += t;
        if (w2 < wv) base += t;
    }
    const unsigned long long lt = (1ull << lane) - 1ull;
    if (live0) {
        int p = base + __popcll(ms0 & lt);
        sA[p] = RA[j0]; sB[p] = RB[j0]; sC[p] = RC[j0];
    }
    if (live1) {
        int p = base + c0 + __popcll(ms1 & lt);
        sA[p] = RA[j1]; sB[p] = RB[j1]; sC[p] = RC[j1];
    }
    __syncthreads();

    // ---- load this thread's 2 points (gather) ----
    const float2* xp = (const float2*)x;
    const int n = min((int)cnt[fat], CELL_CAP);
    const int t1 = tid, t2 = tid + 256;
    const bool v1 = t1 < n, v2 = t2 < n;
    float x1 = 4.f, y1 = 4.f, x2 = 4.f, y2 = 4.f;
    int o1 = 0, o2 = 0;
    if (v1) { o1 = idxl[fat * CELL_CAP + t1]; float2 p = xp[o1]; x1 = p.x; y1 = p.y; }
    if (v2) { o2 = idxl[fat * CELL_CAP + t2]; float2 p = xp[o2]; x2 = p.x; y2 = p.y; }

    float* obase = out + (size_t)set * 2 * N_PTS;

    // ---- phase 2: live centers from LDS (broadcast reads, prefetchable) ----
    if (set == 0) {
        float A0 = 0.f, A1 = 0.f, A2 = 0.f, A3 = 0.f;
        float B0 = 0.f, B1 = 0.f, B2 = 0.f, B3 = 0.f;
        #pragma unroll 2
        for (int t = 0; t < m; ++t) {
            float4 A = sA[t]; float4 K = sB[t]; float k3 = sC[t];
            float u1 = fmaf(x1, A.y, A.x), u2 = fmaf(x1, u1, K.x);
            float u3 = fmaf(y1, A.w, A.z), s1 = fmaf(y1, u3, u2);
            float e1 = EXP2(s1);
            float g1 = fmaf(x2, A.y, A.x), g2 = fmaf(x2, g1, K.x);
            float g3 = fmaf(y2, A.w, A.z), s2 = fmaf(y2, g3, g2);
            float e2 = EXP2(s2);
            A0 = fmaf(K.y, e1, A0); A1 = fmaf(K.z, e1, A1);
            A2 = fmaf(K.w, e1, A2); A3 = fmaf(k3,  e1, A3);
            B0 = fmaf(K.y, e2, B0); B1 = fmaf(K.z, e2, B1);
            B2 = fmaf(K.w, e2, B2); B3 = fmaf(k3,  e2, B3);
        }
        if (v1) { atomicAdd(&obase[o1], fmaf(x1, A0, A1)); atomicAdd(&obase[N_PTS + o1], fmaf(y1, A2, A3)); }
        if (v2) { atomicAdd(&obase[o2], fmaf(x2, B0, B1)); atomicAdd(&obase[N_PTS + o2], fmaf(y2, B2, B3)); }
    } else {
        float A0 = 0.f, A1 = 0.f, A2 = 0.f;
        float B0 = 0.f, B1 = 0.f, B2 = 0.f;
        #pragma unroll 2
        for (int t = 0; t < m; ++t) {
            float4 A = sA[t]; float4 K = sB[t];
            float u1 = fmaf(x1, A.y, A.x), u2 = fmaf(x1, u1, K.x);
            float u3 = fmaf(y1, A.w, A.z), s1 = fmaf(y1, u3, u2);
            float e1 = EXP2(s1);
            float g1 = fmaf(x2, A.y, A.x), g2 = fmaf(x2, g1, K.x);
            float g3 = fmaf(y2, A.w, A.z), s2 = fmaf(y2, g3, g2);
            float e2 = EXP2(s2);
            A0 = fmaf(K.y, e1, A0); A1 = fmaf(K.z, e1, A1); A2 = fmaf(K.w, e1, A2);
            B0 = fmaf(K.y, e2, B0); B1 = fmaf(K.z, e2, B1); B2 = fmaf(K.w, e2, B2);
        }
        if (v1) {
            float r2 = (set == 1) ? fmaf(x1, A1, A2) : fmaf(y1, A1, A2);
            atomicAdd(&obase[o1], A0); atomicAdd(&obase[N_PTS + o1], r2);
        }
        if (v2) {
            float r2 = (set == 1) ? fmaf(x2, B1, B2) : fmaf(y2, B1, B2);
            atomicAdd(&obase[o2], B0); atomicAdd(&obase[N_PTS + o2], r2);
        }
    }

    // ---- residue pass (rare: cells with n > 512; usually exec-z skipped) ----
    for (int t3 = 512 + tid; t3 < n; t3 += 256) {
        int o3 = idxl[fat * CELL_CAP + t3];
        float2 p = xp[o3];
        float x3 = p.x, y3 = p.y;
        float C0 = 0.f, C1 = 0.f, C2 = 0.f, C3 = 0.f;
        for (int t = 0; t < m; ++t) {
            float4 A = sA[t]; float4 K = sB[t]; float k3 = sC[t];
            float u1 = fmaf(x3, A.y, A.x), u2 = fmaf(x3, u1, K.x);
            float u3 = fmaf(y3, A.w, A.z), s3 = fmaf(y3, u3, u2);
            float e = EXP2(s3);
            C0 = fmaf(K.y, e, C0); C1 = fmaf(K.z, e, C1);
            C2 = fmaf(K.w, e, C2); C3 = fmaf(k3,  e, C3);
        }
        float r1, r2;
        if (set == 0)      { r1 = fmaf(x3, C0, C1); r2 = fmaf(y3, C2, C3); }
        else if (set == 1) { r1 = C0;               r2 = fmaf(x3, C1, C2); }
        else               { r1 = C0;               r2 = fmaf(y3, C1, C2); }
        atomicAdd(&obase[o3], r1); atomicAdd(&obase[N_PTS + o3], r2);
    }
}

extern "C" void kernel_launch(void* const* d_in, const int* in_sizes, int n_in,
                              void* d_out, int out_size, void* d_ws, size_t ws_size,
                              hipStream_t stream) {
    const float* x  = (const float*)d_in[0];
    const float* h1 = (const float*)d_in[1];
    const float* c1 = (const float*)d_in[2];
    const float* w1 = (const float*)d_in[3];
    const float* h2 = (const float*)d_in[4];
    const float* c2 = (const float*)d_in[5];
    const float* w2 = (const float*)d_in[6];
    const float* h3 = (const float*)d_in[7];
    const float* c3 = (const float*)d_in[8];
    const float* w3 = (const float*)d_in[9];

    char* ws = (char*)d_ws;
    float4* RA = (float4*)(ws);                            // 49152 B
    float4* RB = (float4*)(ws + 49152);                    // 49152 B
    float*  RC = (float*) (ws + 98304);                    // 12288 B
    float4* RT = (float4*)(ws + 110592);                   // 49152 B
    unsigned int*   cnt  = (unsigned int*)(ws + 159744);   // 512 B
    unsigned short* idxl = (unsigned short*)(ws + 160256); // 196608 B (total ~349 KB)

    // K1: fold constants + zero outputs + zero cell counts
    prep_kernel<<<dim3(12), dim3(256), 0, stream>>>(
        h1, c1, w1, h2, c2, w2, h3, c3, w3, RA, RB, RC, RT, cnt, (float4*)d_out);

    // K2: bucket points into 8x16 fat cells
    bucket_kernel<<<dim3(256), dim3(256), 0, stream>>>(x, cnt, idxl);

    // K3: 3 sets x 128 fat cells x 2 center-chunks = 768 blocks (3/CU exact)
    srbf_main<<<dim3(768), dim3(256), 0, stream>>>(
        x, RA, RB, RC, RT, cnt, idxl, (float*)d_out);
}